// Round 1
// baseline (6875.925 us; speedup 1.0000x reference)
//
#include <hip/hip_runtime.h>
#include <hip/hip_bf16.h>
#include <math.h>

// Problem sizes
#define Bsz 16
#define Ssz 512
#define Tsz 64
#define Hsz 1024
#define Esz 512
#define Vsz 32000
#define G4  4096          // 4*H
#define TD  63            // T-1
#define GREC 64           // persistent-kernel grid (all-resident on 256 CUs)

typedef unsigned short u16;
typedef unsigned int   u32;
typedef unsigned long long u64;
typedef short  s8v  __attribute__((ext_vector_type(8)));  // 8 x bf16 bits
typedef float  f32x4 __attribute__((ext_vector_type(4)));

#define DEV static __device__ __forceinline__

DEV u16 f2bf(float f){ __bf16 h = (__bf16)f; return __builtin_bit_cast(u16, h); }
DEV float bf2f(u16 b){ union { u32 u; float f; } a; a.u = ((u32)b) << 16; return a.f; }
DEV float sig_(float x){ return 1.0f / (1.0f + __expf(-x)); }
DEV f32x4 mfma16(s8v a, s8v b, f32x4 c){
  return __builtin_amdgcn_mfma_f32_16x16x32_bf16(a, b, c, 0, 0, 0);
}

// ---------------- grid barrier (flags in ws, zeroed by k_zero) ----------------
// Light: no fences. h is exchanged via agent-scope atomics (L2-bypassing), and the
// compiler's s_waitcnt vmcnt(0) before s_barrier drains h-stores before the flag
// store, so L3 arrival order gives us the needed ordering. Keeping fences out of
// the step loop keeps Whh/Xe L2-resident (no per-step buffer_inv).
// Heavy: full agent release/acquire fences for normal-store data (enc_outs etc).
template<bool HEAVY>
DEV void gbar(int* flags, int ep){
  __syncthreads();
  if (threadIdx.x == 0){
    if (HEAVY) __builtin_amdgcn_fence(__ATOMIC_RELEASE, "agent");
    __hip_atomic_store(&flags[blockIdx.x], ep, __ATOMIC_RELAXED, __HIP_MEMORY_SCOPE_AGENT);
  }
  if (threadIdx.x < GREC){
    while (__hip_atomic_load(&flags[threadIdx.x], __ATOMIC_RELAXED,
                             __HIP_MEMORY_SCOPE_AGENT) < ep) {}
  }
  __syncthreads();
  if (HEAVY) __builtin_amdgcn_fence(__ATOMIC_ACQUIRE, "agent");
}

// ---------------- fp32 -> bf16 weight conversion ----------------
__global__ void k_conv(const float* __restrict__ src, u16* __restrict__ dst,
                       long n, int src_ld, int lc){
  long base = (long)blockIdx.x * 1024 + threadIdx.x;
  #pragma unroll
  for (int q = 0; q < 4; ++q){
    long j = base + (long)q * 256;
    if (j < n){
      long r = j >> lc;
      long c = j & ((1L << lc) - 1);
      dst[j] = f2bf(src[(size_t)r * src_ld + c]);
    }
  }
}

// zero out[:,0,:] and barrier flags
__global__ void k_zero(float* __restrict__ out, int* __restrict__ flags){
  int i = blockIdx.x * 256 + threadIdx.x;
  if (i < Bsz * Vsz){
    int b = i / Vsz; int v = i - b * Vsz;
    out[(size_t)(b * Tsz) * Vsz + v] = 0.f;
  }
  if (i < GREC) flags[i] = 0;
}

// u[k] = sum_j attn_W[j, k] * align_w[j]   (k < H; only first-H cols matter)
__global__ void k_u(const float* __restrict__ attn_W, const float* __restrict__ align_w,
                    float* __restrict__ u){
  int k = blockIdx.x * 256 + threadIdx.x;
  float s = 0.f;
  for (int j = 0; j < Hsz; ++j) s += attn_W[(size_t)j * (2*Hsz) + k] * align_w[j];
  u[k] = s;
}

// ---------------- generic 128x128 MFMA GEMM: C[m,n] = sum_k A[m,k]*B[n,k] ----------------
// GATHER: A row m gathered from emb[toks[(m&15)*tok_cols + (m>>4)]] (fp32 -> bf16)
// OUTBF : store bf16 to Cb, else fp32 to Cf
// MAPROW: out row = (b*T + t + 1) for m = t*16+b   (final logits scatter)
template<bool GATHER, bool OUTBF, bool HASBIAS, bool MAPROW>
__global__ __launch_bounds__(256) void k_gemm(
    const float* __restrict__ emb, const int* __restrict__ toks, int tok_cols,
    const u16* __restrict__ Abf, const u16* __restrict__ Bbf,
    const float* __restrict__ bias,
    float* __restrict__ Cf, u16* __restrict__ Cb,
    int M, int N, int K)
{
  __shared__ u16 As[128 * 40];   // pad to 40 (80B rows: 16B aligned, 2-way-max banks)
  __shared__ u16 Bs[128 * 40];
  const int tid  = threadIdx.x;
  const int wave = tid >> 6, lane = tid & 63;
  const int qm = wave & 1, qn = wave >> 1;
  const int m0 = blockIdx.y * 128, n0 = blockIdx.x * 128;
  const int r = tid >> 1, half = tid & 1;

  f32x4 acc[4][4];
  #pragma unroll
  for (int i = 0; i < 4; ++i)
    #pragma unroll
    for (int j = 0; j < 4; ++j) acc[i][j] = (f32x4){0.f,0.f,0.f,0.f};

  for (int kk = 0; kk < K; kk += 32){
    // stage A tile [128][32]
    {
      const int m = m0 + r;
      if (GATHER){
        u16 tmp[16];
        if (m < M){
          const int tok = toks[(m & 15) * tok_cols + (m >> 4)];
          const float4* s4 = (const float4*)(emb + (size_t)tok * K + kk + half*16);
          #pragma unroll
          for (int c = 0; c < 4; ++c){
            float4 f = s4[c];
            tmp[c*4+0] = f2bf(f.x); tmp[c*4+1] = f2bf(f.y);
            tmp[c*4+2] = f2bf(f.z); tmp[c*4+3] = f2bf(f.w);
          }
        } else {
          #pragma unroll
          for (int c = 0; c < 16; ++c) tmp[c] = 0;
        }
        *(s8v*)&As[r*40 + half*16]     = *(s8v*)&tmp[0];
        *(s8v*)&As[r*40 + half*16 + 8] = *(s8v*)&tmp[8];
      } else {
        s8v v0 = {0,0,0,0,0,0,0,0}, v1 = {0,0,0,0,0,0,0,0};
        if (m < M){
          const u16* src = Abf + (size_t)m * K + kk + half*16;
          v0 = *(const s8v*)src; v1 = *(const s8v*)(src + 8);
        }
        *(s8v*)&As[r*40 + half*16]     = v0;
        *(s8v*)&As[r*40 + half*16 + 8] = v1;
      }
    }
    // stage B tile [128][32] (N is always a multiple of 128)
    {
      const u16* src = Bbf + (size_t)(n0 + r) * K + kk + half*16;
      *(s8v*)&Bs[r*40 + half*16]     = *(const s8v*)src;
      *(s8v*)&Bs[r*40 + half*16 + 8] = *(const s8v*)(src + 8);
    }
    __syncthreads();
    s8v af[4], bv[4];
    #pragma unroll
    for (int i = 0; i < 4; ++i)
      af[i] = *(s8v*)&As[(qm*64 + i*16 + (lane & 15))*40 + (lane >> 4)*8];
    #pragma unroll
    for (int j = 0; j < 4; ++j)
      bv[j] = *(s8v*)&Bs[(qn*64 + j*16 + (lane & 15))*40 + (lane >> 4)*8];
    #pragma unroll
    for (int i = 0; i < 4; ++i)
      #pragma unroll
      for (int j = 0; j < 4; ++j)
        acc[i][j] = mfma16(af[i], bv[j], acc[i][j]);
    __syncthreads();
  }
  // epilogue: D row = (lane>>4)*4 + reg (M index), col = lane&15 (N index)
  #pragma unroll
  for (int i = 0; i < 4; ++i){
    #pragma unroll
    for (int j = 0; j < 4; ++j){
      const int nn = n0 + qn*64 + j*16 + (lane & 15);
      #pragma unroll
      for (int rr = 0; rr < 4; ++rr){
        const int mm = m0 + qm*64 + i*16 + (lane >> 4)*4 + rr;
        if (mm < M){
          float v = acc[i][j][rr];
          if (HASBIAS) v += bias[nn];
          if (OUTBF){
            Cb[(size_t)mm * N + nn] = f2bf(v);
          } else {
            const int row = MAPROW ? ((mm & 15) * Tsz + (mm >> 4) + 1) : mm;
            Cf[(size_t)row * N + nn] = v;
          }
        }
      }
    }
  }
}

// ---------------- persistent recurrence kernel ----------------
// 64 blocks x 256 threads. Block g owns h-dims [g*16, g*16+16).
// Wave w computes gate w's 16 rows: C[16 batch][16 dims] via 32 chained MFMAs, K=1024.
// A-frags: agent-atomic 8B loads of the shared h (L3-fresh, no fences needed).
// B-frags: normal loads of bf16 Whh rows (L2-resident across steps).
// c state: one fp32 register per thread (thread = (batch,dim)) for the whole kernel.
__global__ __launch_bounds__(256) void k_rec(
    const u16* __restrict__ WhhE, const u16* __restrict__ WhhD,
    const u16* __restrict__ Xe,   const float* __restrict__ Xd,
    const float* __restrict__ u,  const float* __restrict__ dec_Wih,
    const float* __restrict__ dec_b,
    u16* hbuf, u16* enc_outs,
    float* scores, float* ctx, float* addc,
    u16* Hd, int* flags)
{
  __shared__ float lg[4][16][16];
  __shared__ float sw[512];
  __shared__ float red[4];

  const int tid  = threadIdx.x;
  const int g    = blockIdx.x;
  const int wave = tid >> 6, lane = tid & 63;
  const int bu = tid >> 4, du = tid & 15;
  int ep = 0;
  float c_reg = 0.f;

  // zero my slice of h buf0 via agent atomics (readers bypass L2 -> must be in L3)
  if ((du & 1) == 0){
    u32* h32 = (u32*)hbuf;
    __hip_atomic_store(&h32[(bu*Hsz + g*16 + du) >> 1], 0u,
                       __ATOMIC_RELAXED, __HIP_MEMORY_SCOPE_AGENT);
  }
  gbar<false>(flags, ++ep);

  int p = 0;
  // ---------------- encoder: 512 steps ----------------
  #pragma unroll 1
  for (int t = 0; t < Ssz; ++t){
    float xe[4];
    {
      const u16* xr = Xe + ((size_t)(t*Bsz + bu))*G4 + g*16 + du;
      #pragma unroll
      for (int q = 0; q < 4; ++q) xe[q] = bf2f(xr[q*Hsz]);
    }
    f32x4 acc = {0.f,0.f,0.f,0.f};
    {
      const u16* wrow = WhhE + ((size_t)(wave*Hsz + g*16 + (lane & 15)))*Hsz;
      const u16* arow = hbuf + p*(Bsz*Hsz) + (lane & 15)*Hsz;
      const int ko = (lane >> 4)*8;
      #pragma unroll
      for (int kk = 0; kk < 32; ++kk){
        union { u64 q[2]; s8v s; } ua;
        const u64* ap = (const u64*)(arow + kk*32 + ko);
        ua.q[0] = __hip_atomic_load(ap,     __ATOMIC_RELAXED, __HIP_MEMORY_SCOPE_AGENT);
        ua.q[1] = __hip_atomic_load(ap + 1, __ATOMIC_RELAXED, __HIP_MEMORY_SCOPE_AGENT);
        s8v bv = *(const s8v*)(wrow + kk*32 + ko);
        acc = mfma16(ua.s, bv, acc);
      }
    }
    #pragma unroll
    for (int rr = 0; rr < 4; ++rr) lg[wave][(lane >> 4)*4 + rr][lane & 15] = acc[rr];
    __syncthreads();
    float pi = lg[0][bu][du] + xe[0];
    float pf = lg[1][bu][du] + xe[1];
    float pg = lg[2][bu][du] + xe[2];
    float po = lg[3][bu][du] + xe[3];
    float iv = sig_(pi), fv = sig_(pf), gv = tanhf(pg), ov = sig_(po);
    c_reg = fv * c_reg + iv * gv;
    float hv = ov * tanhf(c_reg);
    u16 hb = f2bf(hv);
    enc_outs[((size_t)(t*Bsz + bu))*Hsz + g*16 + du] = hb;   // normal store (fenced later)
    {
      u32 my = (u32)hb;
      u32 nb = __shfl_down(my, 1);
      if ((du & 1) == 0){
        u32 packed = my | (nb << 16);
        u32* h32 = (u32*)(hbuf + (1 - p)*(Bsz*Hsz));
        __hip_atomic_store(&h32[(bu*Hsz + g*16 + du) >> 1], packed,
                           __ATOMIC_RELAXED, __HIP_MEMORY_SCOPE_AGENT);
      }
    }
    p ^= 1;
    gbar<false>(flags, ++ep);
  }
  gbar<true>(flags, ++ep);   // flush enc_outs to L3, invalidate stale copies

  // ---------------- attention scores: block g does s in [g*8, g*8+8) ----------------
  #pragma unroll 1
  for (int si = 0; si < 2; ++si){
    const int s = g*8 + wave*2 + si;
    #pragma unroll 1
    for (int b = 0; b < Bsz; ++b){
      const u16* er = enc_outs + ((size_t)(s*Bsz + b))*Hsz;
      float sum = 0.f;
      #pragma unroll
      for (int j = 0; j < 16; ++j) sum += bf2f(er[lane + 64*j]) * u[lane + 64*j];
      #pragma unroll
      for (int off = 32; off; off >>= 1) sum += __shfl_xor(sum, off);
      if (lane == 0) scores[b*Ssz + s] = sum;
    }
  }
  gbar<true>(flags, ++ep);

  // ---------------- softmax + ctx: blocks 0..15 (block = batch) ----------------
  if (g < Bsz){
    const int b = g;
    float s0 = scores[b*Ssz + tid], s1 = scores[b*Ssz + tid + 256];
    float m = fmaxf(s0, s1);
    #pragma unroll
    for (int off = 32; off; off >>= 1) m = fmaxf(m, __shfl_xor(m, off));
    if (lane == 0) red[wave] = m;
    __syncthreads();
    m = fmaxf(fmaxf(red[0], red[1]), fmaxf(red[2], red[3]));
    float e0 = __expf(s0 - m), e1 = __expf(s1 - m);
    sw[tid] = e0; sw[tid + 256] = e1;
    float zs = e0 + e1;
    #pragma unroll
    for (int off = 32; off; off >>= 1) zs += __shfl_xor(zs, off);
    __syncthreads();
    if (lane == 0) red[wave] = zs;
    __syncthreads();
    const float inv = 1.f / (red[0] + red[1] + red[2] + red[3]);
    float a0 = 0.f, a1 = 0.f, a2 = 0.f, a3 = 0.f;
    #pragma unroll 1
    for (int s = 0; s < Ssz; ++s){
      const float w = sw[s];
      const u16* er = enc_outs + ((size_t)(s*Bsz + b))*Hsz;
      a0 += w * bf2f(er[tid]);       a1 += w * bf2f(er[tid + 256]);
      a2 += w * bf2f(er[tid + 512]); a3 += w * bf2f(er[tid + 768]);
    }
    ctx[b*Hsz + tid]       = a0*inv; ctx[b*Hsz + tid + 256] = a1*inv;
    ctx[b*Hsz + tid + 512] = a2*inv; ctx[b*Hsz + tid + 768] = a3*inv;
  }
  gbar<true>(flags, ++ep);

  // ---------------- addc[b,gcol] = ctx[b] . dec_Wih[gcol, E:] + dec_b[gcol] ----------------
  #pragma unroll 1
  for (int i = 0; i < 16; ++i){
    const int gcol = g*64 + wave*16 + i;
    const float* wr = dec_Wih + (size_t)gcol*(Esz + Hsz) + Esz;
    float wreg[16];
    #pragma unroll
    for (int j = 0; j < 16; ++j) wreg[j] = wr[lane + 64*j];
    #pragma unroll 1
    for (int b = 0; b < Bsz; ++b){
      const float* cr = ctx + b*Hsz;
      float s = 0.f;
      #pragma unroll
      for (int j = 0; j < 16; ++j) s += wreg[j] * cr[lane + 64*j];
      #pragma unroll
      for (int off = 32; off; off >>= 1) s += __shfl_xor(s, off);
      if (lane == 0) addc[b*G4 + gcol] = s + dec_b[gcol];
    }
  }
  gbar<true>(flags, ++ep);

  // ---------------- decoder: 63 steps (c_reg carries over = reference init) ----------------
  #pragma unroll 1
  for (int t = 0; t < TD; ++t){
    float xd[4];
    {
      const float* xr = Xd + ((size_t)(t*Bsz + bu))*G4 + g*16 + du;
      const float* ar = addc + bu*G4 + g*16 + du;
      #pragma unroll
      for (int q = 0; q < 4; ++q) xd[q] = xr[q*Hsz] + ar[q*Hsz];
    }
    f32x4 acc = {0.f,0.f,0.f,0.f};
    {
      const u16* wrow = WhhD + ((size_t)(wave*Hsz + g*16 + (lane & 15)))*Hsz;
      const u16* arow = hbuf + p*(Bsz*Hsz) + (lane & 15)*Hsz;
      const int ko = (lane >> 4)*8;
      #pragma unroll
      for (int kk = 0; kk < 32; ++kk){
        union { u64 q[2]; s8v s; } ua;
        const u64* ap = (const u64*)(arow + kk*32 + ko);
        ua.q[0] = __hip_atomic_load(ap,     __ATOMIC_RELAXED, __HIP_MEMORY_SCOPE_AGENT);
        ua.q[1] = __hip_atomic_load(ap + 1, __ATOMIC_RELAXED, __HIP_MEMORY_SCOPE_AGENT);
        s8v bv = *(const s8v*)(wrow + kk*32 + ko);
        acc = mfma16(ua.s, bv, acc);
      }
    }
    #pragma unroll
    for (int rr = 0; rr < 4; ++rr) lg[wave][(lane >> 4)*4 + rr][lane & 15] = acc[rr];
    __syncthreads();
    float pi = lg[0][bu][du] + xd[0];
    float pf = lg[1][bu][du] + xd[1];
    float pg = lg[2][bu][du] + xd[2];
    float po = lg[3][bu][du] + xd[3];
    float iv = sig_(pi), fv = sig_(pf), gv = tanhf(pg), ov = sig_(po);
    c_reg = fv * c_reg + iv * gv;
    float hv = ov * tanhf(c_reg);
    u16 hb = f2bf(hv);
    Hd[((size_t)(t*Bsz + bu))*Hsz + g*16 + du] = hb;  // normal store; kernel-end flush
    {
      u32 my = (u32)hb;
      u32 nb = __shfl_down(my, 1);
      if ((du & 1) == 0){
        u32 packed = my | (nb << 16);
        u32* h32 = (u32*)(hbuf + (1 - p)*(Bsz*Hsz));
        __hip_atomic_store(&h32[(bu*Hsz + g*16 + du) >> 1], packed,
                           __ATOMIC_RELAXED, __HIP_MEMORY_SCOPE_AGENT);
      }
    }
    p ^= 1;
    gbar<false>(flags, ++ep);
  }
}

// ---------------- host side ----------------
extern "C" void kernel_launch(void* const* d_in, const int* in_sizes, int n_in,
                              void* d_out, int out_size, void* d_ws, size_t ws_size,
                              hipStream_t stream)
{
  const int*   source  = (const int*)  d_in[0];
  const int*   target  = (const int*)  d_in[1];
  const float* emb_enc = (const float*)d_in[2];
  const float* enc_Wih = (const float*)d_in[3];
  const float* enc_Whh = (const float*)d_in[4];
  const float* enc_b   = (const float*)d_in[5];
  const float* attn_W  = (const float*)d_in[6];
  const float* align_w = (const float*)d_in[8];   // attn_b / align_b cancel in softmax
  const float* emb_dec = (const float*)d_in[10];
  const float* dec_Wih = (const float*)d_in[11];
  const float* dec_Whh = (const float*)d_in[12];
  const float* dec_b   = (const float*)d_in[13];
  const float* out_W   = (const float*)d_in[14];
  const float* out_b   = (const float*)d_in[15];
  float* out = (float*)d_out;

  // workspace carve-up (~193 MB total)
  char* ws = (char*)d_ws;
  size_t off = 0;
  auto alloc = [&](size_t bytes)->char* {
    char* p = ws + off; off += (bytes + 255) & ~(size_t)255; return p;
  };
  float* u_v     = (float*)alloc((size_t)Hsz * 4);
  u16* wE_ih     = (u16*)  alloc((size_t)G4 * Esz * 2);
  u16* wE_hh     = (u16*)  alloc((size_t)G4 * Hsz * 2);
  u16* wD_ihE    = (u16*)  alloc((size_t)G4 * Esz * 2);
  u16* wD_hh     = (u16*)  alloc((size_t)G4 * Hsz * 2);
  u16* wOut      = (u16*)  alloc((size_t)Vsz * Hsz * 2);
  u16* Xe        = (u16*)  alloc((size_t)(Bsz*Ssz) * G4 * 2);
  float* Xdv     = (float*)alloc((size_t)(TD*Bsz) * G4 * 4);
  u16* enc_outs  = (u16*)  alloc((size_t)(Bsz*Ssz) * Hsz * 2);
  u16* hbuf      = (u16*)  alloc((size_t)2 * Bsz * Hsz * 2);
  float* scores  = (float*)alloc((size_t)Bsz * Ssz * 4);
  float* ctx     = (float*)alloc((size_t)Bsz * Hsz * 4);
  float* addc    = (float*)alloc((size_t)Bsz * G4 * 4);
  u16* Hd        = (u16*)  alloc((size_t)(TD*Bsz) * Hsz * 2);
  int* flags     = (int*)  alloc((size_t)GREC * 4);

  // 1) weight conversions fp32 -> bf16
  auto cv = [&](const float* s, u16* d, long n, int ld, int lc){
    k_conv<<<dim3((unsigned)((n + 1023) / 1024)), 256, 0, stream>>>(s, d, n, ld, lc);
  };
  cv(enc_Wih, wE_ih, (long)G4 * Esz, Esz, 9);
  cv(enc_Whh, wE_hh, (long)G4 * Hsz, Hsz, 10);
  cv(dec_Wih, wD_ihE,(long)G4 * Esz, Esz + Hsz, 9);   // first E cols of [4H, E+H]
  cv(dec_Whh, wD_hh, (long)G4 * Hsz, Hsz, 10);
  cv(out_W,   wOut,  (long)Vsz * Hsz, Hsz, 10);

  // 2) zero out[:,0,:] + flags; attention score vector u
  k_zero<<<dim3((Bsz*Vsz + 255) / 256), 256, 0, stream>>>(out, flags);
  k_u<<<dim3(Hsz / 256), 256, 0, stream>>>(attn_W, align_w, u_v);

  // 3) encoder input preacts: Xe[s*16+b, :] = emb_enc[source] @ Wih.T + enc_b  (bf16)
  k_gemm<true,  true,  true,  false><<<dim3(G4/128, (Bsz*Ssz)/128), 256, 0, stream>>>(
      emb_enc, source, Ssz, nullptr, wE_ih, enc_b, nullptr, Xe, Bsz*Ssz, G4, Esz);

  // 4) decoder input preacts (embedding part): Xd[t*16+b, :] = emb_dec[tok] @ WihE.T (fp32)
  k_gemm<true,  false, false, false><<<dim3(G4/128, (TD*Bsz + 127)/128), 256, 0, stream>>>(
      emb_dec, target, Tsz, nullptr, wD_ihE, nullptr, Xdv, nullptr, TD*Bsz, G4, Esz);

  // 5) persistent recurrence: encoder 512 steps + attention + decoder 63 steps
  k_rec<<<dim3(GREC), 256, 0, stream>>>(wE_hh, wD_hh, Xe, Xdv, u_v, dec_Wih, dec_b,
                                        hbuf, enc_outs, scores, ctx, addc, Hd, flags);

  // 6) logits: out[b, t+1, :] = Hd[t*16+b, :] @ out_W.T + out_b
  k_gemm<false, false, true,  true ><<<dim3(Vsz/128, (TD*Bsz + 127)/128), 256, 0, stream>>>(
      nullptr, nullptr, 0, Hd, wOut, out_b, out, nullptr, TD*Bsz, Vsz, Hsz);

  (void)in_sizes; (void)n_in; (void)out_size; (void)ws_size;
}

// Round 2
// 2511.457 us; speedup vs baseline: 2.7378x; 2.7378x over previous
//
#include <hip/hip_runtime.h>
#include <hip/hip_bf16.h>
#include <math.h>

// Problem sizes
#define Bsz 16
#define Ssz 512
#define Tsz 64
#define Hsz 1024
#define Esz 512
#define Vsz 32000
#define G4  4096          // 4*H
#define TD  63            // T-1
#define GREC 64           // persistent-kernel grid (all-resident on 256 CUs)
#define FPAD 64           // flag padding (ints): one 256B line per flag

typedef unsigned short u16;
typedef unsigned int   u32;
typedef unsigned long long u64;
typedef short  s8v  __attribute__((ext_vector_type(8)));  // 8 x bf16 bits
typedef float  f32x4 __attribute__((ext_vector_type(4)));

#define DEV static __device__ __forceinline__

DEV u16 f2bf(float f){ __bf16 h = (__bf16)f; return __builtin_bit_cast(u16, h); }
DEV float bf2f(u16 b){ union { u32 u; float f; } a; a.u = ((u32)b) << 16; return a.f; }
DEV float sig_(float x){ return 1.0f / (1.0f + __expf(-x)); }
DEV float tanh_(float x){ return 1.0f - 2.0f / (1.0f + __expf(2.0f * x)); }
DEV f32x4 mfma16(s8v a, s8v b, f32x4 c){
  return __builtin_amdgcn_mfma_f32_16x16x32_bf16(a, b, c, 0, 0, 0);
}

// ---------------- grid barrier (flags in ws, zeroed by k_zero) ----------------
// Light: no fences. h is exchanged via agent-scope atomics (L2-bypassing); the
// s_waitcnt vmcnt(0) before s_barrier drains h-stores before the flag store.
// Heavy: full agent release/acquire fences for normal-store data (enc_outs etc).
// Flags padded to one 256B line each to avoid L3 line contention from pollers.
template<bool HEAVY>
DEV void gbar(int* flags, int ep){
  __syncthreads();
  if (threadIdx.x == 0){
    if (HEAVY) __builtin_amdgcn_fence(__ATOMIC_RELEASE, "agent");
    __hip_atomic_store(&flags[blockIdx.x * FPAD], ep, __ATOMIC_RELAXED, __HIP_MEMORY_SCOPE_AGENT);
  }
  if (threadIdx.x < GREC){
    while (__hip_atomic_load(&flags[threadIdx.x * FPAD], __ATOMIC_RELAXED,
                             __HIP_MEMORY_SCOPE_AGENT) < ep)
      __builtin_amdgcn_s_sleep(1);
  }
  __syncthreads();
  if (HEAVY) __builtin_amdgcn_fence(__ATOMIC_ACQUIRE, "agent");
}

// ---------------- fp32 -> bf16 weight conversion ----------------
__global__ void k_conv(const float* __restrict__ src, u16* __restrict__ dst,
                       long n, int src_ld, int lc){
  long base = (long)blockIdx.x * 1024 + threadIdx.x;
  #pragma unroll
  for (int q = 0; q < 4; ++q){
    long j = base + (long)q * 256;
    if (j < n){
      long r = j >> lc;
      long c = j & ((1L << lc) - 1);
      dst[j] = f2bf(src[(size_t)r * src_ld + c]);
    }
  }
}

// zero out[:,0,:] and barrier flags
__global__ void k_zero(float* __restrict__ out, int* __restrict__ flags){
  int i = blockIdx.x * 256 + threadIdx.x;
  if (i < Bsz * Vsz){
    int b = i / Vsz; int v = i - b * Vsz;
    out[(size_t)(b * Tsz) * Vsz + v] = 0.f;
  }
  if (i < GREC * FPAD) flags[i] = 0;
}

// u[k] = sum_j attn_W[j, k] * align_w[j]   (k < H; only first-H cols matter)
__global__ void k_u(const float* __restrict__ attn_W, const float* __restrict__ align_w,
                    float* __restrict__ u){
  int k = blockIdx.x * 256 + threadIdx.x;
  float s = 0.f;
  for (int j = 0; j < Hsz; ++j) s += attn_W[(size_t)j * (2*Hsz) + k] * align_w[j];
  u[k] = s;
}

// ---------------- generic 128x128 MFMA GEMM: C[m,n] = sum_k A[m,k]*B[n,k] ----------------
template<bool GATHER, bool OUTBF, bool HASBIAS, bool MAPROW>
__global__ __launch_bounds__(256) void k_gemm(
    const float* __restrict__ emb, const int* __restrict__ toks, int tok_cols,
    const u16* __restrict__ Abf, const u16* __restrict__ Bbf,
    const float* __restrict__ bias,
    float* __restrict__ Cf, u16* __restrict__ Cb,
    int M, int N, int K)
{
  __shared__ u16 As[128 * 40];   // pad to 40 (80B rows: 16B aligned, 2-way-max banks)
  __shared__ u16 Bs[128 * 40];
  const int tid  = threadIdx.x;
  const int wave = tid >> 6, lane = tid & 63;
  const int qm = wave & 1, qn = wave >> 1;
  const int m0 = blockIdx.y * 128, n0 = blockIdx.x * 128;
  const int r = tid >> 1, half = tid & 1;

  f32x4 acc[4][4];
  #pragma unroll
  for (int i = 0; i < 4; ++i)
    #pragma unroll
    for (int j = 0; j < 4; ++j) acc[i][j] = (f32x4){0.f,0.f,0.f,0.f};

  for (int kk = 0; kk < K; kk += 32){
    // stage A tile [128][32]
    {
      const int m = m0 + r;
      if (GATHER){
        u16 tmp[16];
        if (m < M){
          const int tok = toks[(m & 15) * tok_cols + (m >> 4)];
          const float4* s4 = (const float4*)(emb + (size_t)tok * K + kk + half*16);
          #pragma unroll
          for (int c = 0; c < 4; ++c){
            float4 f = s4[c];
            tmp[c*4+0] = f2bf(f.x); tmp[c*4+1] = f2bf(f.y);
            tmp[c*4+2] = f2bf(f.z); tmp[c*4+3] = f2bf(f.w);
          }
        } else {
          #pragma unroll
          for (int c = 0; c < 16; ++c) tmp[c] = 0;
        }
        *(s8v*)&As[r*40 + half*16]     = *(s8v*)&tmp[0];
        *(s8v*)&As[r*40 + half*16 + 8] = *(s8v*)&tmp[8];
      } else {
        s8v v0 = {0,0,0,0,0,0,0,0}, v1 = {0,0,0,0,0,0,0,0};
        if (m < M){
          const u16* src = Abf + (size_t)m * K + kk + half*16;
          v0 = *(const s8v*)src; v1 = *(const s8v*)(src + 8);
        }
        *(s8v*)&As[r*40 + half*16]     = v0;
        *(s8v*)&As[r*40 + half*16 + 8] = v1;
      }
    }
    // stage B tile [128][32] (N is always a multiple of 128)
    {
      const u16* src = Bbf + (size_t)(n0 + r) * K + kk + half*16;
      *(s8v*)&Bs[r*40 + half*16]     = *(const s8v*)src;
      *(s8v*)&Bs[r*40 + half*16 + 8] = *(const s8v*)(src + 8);
    }
    __syncthreads();
    s8v af[4], bv[4];
    #pragma unroll
    for (int i = 0; i < 4; ++i)
      af[i] = *(s8v*)&As[(qm*64 + i*16 + (lane & 15))*40 + (lane >> 4)*8];
    #pragma unroll
    for (int j = 0; j < 4; ++j)
      bv[j] = *(s8v*)&Bs[(qn*64 + j*16 + (lane & 15))*40 + (lane >> 4)*8];
    #pragma unroll
    for (int i = 0; i < 4; ++i)
      #pragma unroll
      for (int j = 0; j < 4; ++j)
        acc[i][j] = mfma16(af[i], bv[j], acc[i][j]);
    __syncthreads();
  }
  // epilogue: D row = (lane>>4)*4 + reg (M index), col = lane&15 (N index)
  #pragma unroll
  for (int i = 0; i < 4; ++i){
    #pragma unroll
    for (int j = 0; j < 4; ++j){
      const int nn = n0 + qn*64 + j*16 + (lane & 15);
      #pragma unroll
      for (int rr = 0; rr < 4; ++rr){
        const int mm = m0 + qm*64 + i*16 + (lane >> 4)*4 + rr;
        if (mm < M){
          float v = acc[i][j][rr];
          if (HASBIAS) v += bias[nn];
          if (OUTBF){
            Cb[(size_t)mm * N + nn] = f2bf(v);
          } else {
            const int row = MAPROW ? ((mm & 15) * Tsz + (mm >> 4) + 1) : mm;
            Cf[(size_t)row * N + nn] = v;
          }
        }
      }
    }
  }
}

// ---------------- persistent recurrence kernel ----------------
// 64 blocks x 256 threads, 1 block/CU. Block g owns h-dims [g*16, g*16+16).
// Per step: stage full h (16x1024 bf16 = 32KB) into LDS via 16 batched agent-
// atomic 8B loads per thread (ONE L3 round trip, not 32), XOR-swizzled 16B
// chunks. Whh B-fragments are step-invariant -> preloaded into 128 VGPRs once
// per phase. Inner loop = ds_read_b128 + mfma only, 2 independent acc chains.
__global__ __launch_bounds__(256, 1) void k_rec(
    const u16* __restrict__ WhhE, const u16* __restrict__ WhhD,
    const u16* __restrict__ Xe,   const float* __restrict__ Xd,
    const float* __restrict__ u,  const float* __restrict__ dec_Wih,
    const float* __restrict__ dec_b,
    u16* hbuf, u16* enc_outs,
    float* scores, float* ctx, float* addc,
    u16* Hd, int* flags)
{
  __shared__ u64 hs[4096];          // 32 KB staged h, 16B-chunk xor swizzle
  __shared__ float lg[4][16][16];
  __shared__ float sw[512];
  __shared__ float red[4];

  const int tid  = threadIdx.x;
  const int g    = blockIdx.x;
  const int wave = tid >> 6, lane = tid & 63;
  const int bu = tid >> 4, du = tid & 15;
  int ep = 0;
  float c_reg = 0.f;

  // zero my slice of h buf0 via agent atomics (readers bypass L2 -> must be in L3)
  if ((du & 1) == 0){
    u32* h32 = (u32*)hbuf;
    __hip_atomic_store(&h32[(bu*Hsz + g*16 + du) >> 1], 0u,
                       __ATOMIC_RELAXED, __HIP_MEMORY_SCOPE_AGENT);
  }
  gbar<false>(flags, ++ep);

  // B fragments (Whh rows for my gate/dims) are step-invariant: keep in VGPRs.
  s8v bfr[32];
  {
    const u16* wrow = WhhE + ((size_t)(wave*Hsz + g*16 + (lane & 15)))*Hsz + (lane >> 4)*8;
    #pragma unroll
    for (int kk = 0; kk < 32; ++kk) bfr[kk] = *(const s8v*)(wrow + kk*32);
  }

  int p = 0;
  // ---------------- encoder: 512 steps ----------------
  #pragma unroll 1
  for (int t = 0; t < Ssz; ++t){
    float xe[4];
    {
      const u16* xr = Xe + ((size_t)(t*Bsz + bu))*G4 + g*16 + du;
      #pragma unroll
      for (int q = 0; q < 4; ++q) xe[q] = bf2f(xr[q*Hsz]);
    }
    // stage h -> LDS (batched independent atomic loads, one drain)
    {
      const u64* hsrc = (const u64*)(hbuf + p*(Bsz*Hsz));
      u64 v[16];
      #pragma unroll
      for (int i = 0; i < 16; ++i)
        v[i] = __hip_atomic_load(hsrc + i*256 + tid, __ATOMIC_RELAXED, __HIP_MEMORY_SCOPE_AGENT);
      #pragma unroll
      for (int i = 0; i < 16; ++i){
        const int c   = i*256 + tid;        // 8B granule index
        const int r   = c >> 8;             // batch row 0..15
        const int g8  = c & 255;
        const int c16 = (g8 >> 1) ^ (r & 7);
        hs[r*256 + c16*2 + (g8 & 1)] = v[i];
      }
    }
    __syncthreads();
    f32x4 acc0 = {0.f,0.f,0.f,0.f}, acc1 = {0.f,0.f,0.f,0.f};
    {
      const int r = lane & 15, q = lane >> 4;
      const u64* hrow = hs + r*256;
      #pragma unroll
      for (int kk = 0; kk < 16; ++kk){
        s8v a0 = *(const s8v*)(hrow + (((kk*4      + q) ^ (r & 7)) << 1));
        acc0 = mfma16(a0, bfr[kk], acc0);
        s8v a1 = *(const s8v*)(hrow + ((((kk+16)*4 + q) ^ (r & 7)) << 1));
        acc1 = mfma16(a1, bfr[kk+16], acc1);
      }
    }
    f32x4 acc = acc0 + acc1;
    #pragma unroll
    for (int rr = 0; rr < 4; ++rr) lg[wave][(lane >> 4)*4 + rr][lane & 15] = acc[rr];
    __syncthreads();
    float pi = lg[0][bu][du] + xe[0];
    float pf = lg[1][bu][du] + xe[1];
    float pg = lg[2][bu][du] + xe[2];
    float po = lg[3][bu][du] + xe[3];
    float iv = sig_(pi), fv = sig_(pf), gv = tanh_(pg), ov = sig_(po);
    c_reg = fv * c_reg + iv * gv;
    float hv = ov * tanh_(c_reg);
    u16 hb = f2bf(hv);
    enc_outs[((size_t)(t*Bsz + bu))*Hsz + g*16 + du] = hb;   // normal store (fenced later)
    {
      u32 my = (u32)hb;
      u32 nb = __shfl_down(my, 1);
      if ((du & 1) == 0){
        u32 packed = my | (nb << 16);
        u32* h32 = (u32*)(hbuf + (1 - p)*(Bsz*Hsz));
        __hip_atomic_store(&h32[(bu*Hsz + g*16 + du) >> 1], packed,
                           __ATOMIC_RELAXED, __HIP_MEMORY_SCOPE_AGENT);
      }
    }
    p ^= 1;
    gbar<false>(flags, ++ep);
  }
  gbar<true>(flags, ++ep);   // flush enc_outs to L3, invalidate stale copies

  // ---------------- attention scores: block g does s in [g*8, g*8+8) ----------------
  #pragma unroll 1
  for (int si = 0; si < 2; ++si){
    const int s = g*8 + wave*2 + si;
    #pragma unroll 1
    for (int b = 0; b < Bsz; ++b){
      const u16* er = enc_outs + ((size_t)(s*Bsz + b))*Hsz;
      float sum = 0.f;
      #pragma unroll
      for (int j = 0; j < 16; ++j) sum += bf2f(er[lane + 64*j]) * u[lane + 64*j];
      #pragma unroll
      for (int off = 32; off; off >>= 1) sum += __shfl_xor(sum, off);
      if (lane == 0) scores[b*Ssz + s] = sum;
    }
  }
  gbar<true>(flags, ++ep);

  // ---------------- softmax + ctx: blocks 0..15 (block = batch) ----------------
  if (g < Bsz){
    const int b = g;
    float s0 = scores[b*Ssz + tid], s1 = scores[b*Ssz + tid + 256];
    float m = fmaxf(s0, s1);
    #pragma unroll
    for (int off = 32; off; off >>= 1) m = fmaxf(m, __shfl_xor(m, off));
    if (lane == 0) red[wave] = m;
    __syncthreads();
    m = fmaxf(fmaxf(red[0], red[1]), fmaxf(red[2], red[3]));
    float e0 = __expf(s0 - m), e1 = __expf(s1 - m);
    sw[tid] = e0; sw[tid + 256] = e1;
    float zs = e0 + e1;
    #pragma unroll
    for (int off = 32; off; off >>= 1) zs += __shfl_xor(zs, off);
    __syncthreads();
    if (lane == 0) red[wave] = zs;
    __syncthreads();
    const float inv = 1.f / (red[0] + red[1] + red[2] + red[3]);
    float a0 = 0.f, a1 = 0.f, a2 = 0.f, a3 = 0.f;
    #pragma unroll 1
    for (int s = 0; s < Ssz; ++s){
      const float w = sw[s];
      const u16* er = enc_outs + ((size_t)(s*Bsz + b))*Hsz;
      a0 += w * bf2f(er[tid]);       a1 += w * bf2f(er[tid + 256]);
      a2 += w * bf2f(er[tid + 512]); a3 += w * bf2f(er[tid + 768]);
    }
    ctx[b*Hsz + tid]       = a0*inv; ctx[b*Hsz + tid + 256] = a1*inv;
    ctx[b*Hsz + tid + 512] = a2*inv; ctx[b*Hsz + tid + 768] = a3*inv;
  }
  gbar<true>(flags, ++ep);

  // ---------------- addc[b,gcol] = ctx[b] . dec_Wih[gcol, E:] + dec_b[gcol] ----------------
  #pragma unroll 1
  for (int i = 0; i < 16; ++i){
    const int gcol = g*64 + wave*16 + i;
    const float* wr = dec_Wih + (size_t)gcol*(Esz + Hsz) + Esz;
    float wreg[16];
    #pragma unroll
    for (int j = 0; j < 16; ++j) wreg[j] = wr[lane + 64*j];
    #pragma unroll 1
    for (int b = 0; b < Bsz; ++b){
      const float* cr = ctx + b*Hsz;
      float s = 0.f;
      #pragma unroll
      for (int j = 0; j < 16; ++j) s += wreg[j] * cr[lane + 64*j];
      #pragma unroll
      for (int off = 32; off; off >>= 1) s += __shfl_xor(s, off);
      if (lane == 0) addc[b*G4 + gcol] = s + dec_b[gcol];
    }
  }
  gbar<true>(flags, ++ep);

  // reload step-invariant B fragments for decoder Whh
  {
    const u16* wrow = WhhD + ((size_t)(wave*Hsz + g*16 + (lane & 15)))*Hsz + (lane >> 4)*8;
    #pragma unroll
    for (int kk = 0; kk < 32; ++kk) bfr[kk] = *(const s8v*)(wrow + kk*32);
  }

  // ---------------- decoder: 63 steps (c_reg carries over = reference init) ----------------
  #pragma unroll 1
  for (int t = 0; t < TD; ++t){
    float xd[4];
    {
      const float* xr = Xd + ((size_t)(t*Bsz + bu))*G4 + g*16 + du;
      const float* ar = addc + bu*G4 + g*16 + du;
      #pragma unroll
      for (int q = 0; q < 4; ++q) xd[q] = xr[q*Hsz] + ar[q*Hsz];
    }
    {
      const u64* hsrc = (const u64*)(hbuf + p*(Bsz*Hsz));
      u64 v[16];
      #pragma unroll
      for (int i = 0; i < 16; ++i)
        v[i] = __hip_atomic_load(hsrc + i*256 + tid, __ATOMIC_RELAXED, __HIP_MEMORY_SCOPE_AGENT);
      #pragma unroll
      for (int i = 0; i < 16; ++i){
        const int c   = i*256 + tid;
        const int r   = c >> 8;
        const int g8  = c & 255;
        const int c16 = (g8 >> 1) ^ (r & 7);
        hs[r*256 + c16*2 + (g8 & 1)] = v[i];
      }
    }
    __syncthreads();
    f32x4 acc0 = {0.f,0.f,0.f,0.f}, acc1 = {0.f,0.f,0.f,0.f};
    {
      const int r = lane & 15, q = lane >> 4;
      const u64* hrow = hs + r*256;
      #pragma unroll
      for (int kk = 0; kk < 16; ++kk){
        s8v a0 = *(const s8v*)(hrow + (((kk*4      + q) ^ (r & 7)) << 1));
        acc0 = mfma16(a0, bfr[kk], acc0);
        s8v a1 = *(const s8v*)(hrow + ((((kk+16)*4 + q) ^ (r & 7)) << 1));
        acc1 = mfma16(a1, bfr[kk+16], acc1);
      }
    }
    f32x4 acc = acc0 + acc1;
    #pragma unroll
    for (int rr = 0; rr < 4; ++rr) lg[wave][(lane >> 4)*4 + rr][lane & 15] = acc[rr];
    __syncthreads();
    float pi = lg[0][bu][du] + xd[0];
    float pf = lg[1][bu][du] + xd[1];
    float pg = lg[2][bu][du] + xd[2];
    float po = lg[3][bu][du] + xd[3];
    float iv = sig_(pi), fv = sig_(pf), gv = tanh_(pg), ov = sig_(po);
    c_reg = fv * c_reg + iv * gv;
    float hv = ov * tanh_(c_reg);
    u16 hb = f2bf(hv);
    Hd[((size_t)(t*Bsz + bu))*Hsz + g*16 + du] = hb;  // normal store; kernel-end flush
    {
      u32 my = (u32)hb;
      u32 nb = __shfl_down(my, 1);
      if ((du & 1) == 0){
        u32 packed = my | (nb << 16);
        u32* h32 = (u32*)(hbuf + (1 - p)*(Bsz*Hsz));
        __hip_atomic_store(&h32[(bu*Hsz + g*16 + du) >> 1], packed,
                           __ATOMIC_RELAXED, __HIP_MEMORY_SCOPE_AGENT);
      }
    }
    p ^= 1;
    gbar<false>(flags, ++ep);
  }
}

// ---------------- host side ----------------
extern "C" void kernel_launch(void* const* d_in, const int* in_sizes, int n_in,
                              void* d_out, int out_size, void* d_ws, size_t ws_size,
                              hipStream_t stream)
{
  const int*   source  = (const int*)  d_in[0];
  const int*   target  = (const int*)  d_in[1];
  const float* emb_enc = (const float*)d_in[2];
  const float* enc_Wih = (const float*)d_in[3];
  const float* enc_Whh = (const float*)d_in[4];
  const float* enc_b   = (const float*)d_in[5];
  const float* attn_W  = (const float*)d_in[6];
  const float* align_w = (const float*)d_in[8];   // attn_b / align_b cancel in softmax
  const float* emb_dec = (const float*)d_in[10];
  const float* dec_Wih = (const float*)d_in[11];
  const float* dec_Whh = (const float*)d_in[12];
  const float* dec_b   = (const float*)d_in[13];
  const float* out_W   = (const float*)d_in[14];
  const float* out_b   = (const float*)d_in[15];
  float* out = (float*)d_out;

  // workspace carve-up (~193 MB total)
  char* ws = (char*)d_ws;
  size_t off = 0;
  auto alloc = [&](size_t bytes)->char* {
    char* p = ws + off; off += (bytes + 255) & ~(size_t)255; return p;
  };
  float* u_v     = (float*)alloc((size_t)Hsz * 4);
  u16* wE_ih     = (u16*)  alloc((size_t)G4 * Esz * 2);
  u16* wE_hh     = (u16*)  alloc((size_t)G4 * Hsz * 2);
  u16* wD_ihE    = (u16*)  alloc((size_t)G4 * Esz * 2);
  u16* wD_hh     = (u16*)  alloc((size_t)G4 * Hsz * 2);
  u16* wOut      = (u16*)  alloc((size_t)Vsz * Hsz * 2);
  u16* Xe        = (u16*)  alloc((size_t)(Bsz*Ssz) * G4 * 2);
  float* Xdv     = (float*)alloc((size_t)(TD*Bsz) * G4 * 4);
  u16* enc_outs  = (u16*)  alloc((size_t)(Bsz*Ssz) * Hsz * 2);
  u16* hbuf      = (u16*)  alloc((size_t)2 * Bsz * Hsz * 2);
  float* scores  = (float*)alloc((size_t)Bsz * Ssz * 4);
  float* ctx     = (float*)alloc((size_t)Bsz * Hsz * 4);
  float* addc    = (float*)alloc((size_t)Bsz * G4 * 4);
  u16* Hd        = (u16*)  alloc((size_t)(TD*Bsz) * Hsz * 2);
  int* flags     = (int*)  alloc((size_t)GREC * FPAD * 4);

  // 1) weight conversions fp32 -> bf16
  auto cv = [&](const float* s, u16* d, long n, int ld, int lc){
    k_conv<<<dim3((unsigned)((n + 1023) / 1024)), 256, 0, stream>>>(s, d, n, ld, lc);
  };
  cv(enc_Wih, wE_ih, (long)G4 * Esz, Esz, 9);
  cv(enc_Whh, wE_hh, (long)G4 * Hsz, Hsz, 10);
  cv(dec_Wih, wD_ihE,(long)G4 * Esz, Esz + Hsz, 9);   // first E cols of [4H, E+H]
  cv(dec_Whh, wD_hh, (long)G4 * Hsz, Hsz, 10);
  cv(out_W,   wOut,  (long)Vsz * Hsz, Hsz, 10);

  // 2) zero out[:,0,:] + flags; attention score vector u
  k_zero<<<dim3((Bsz*Vsz + 255) / 256), 256, 0, stream>>>(out, flags);
  k_u<<<dim3(Hsz / 256), 256, 0, stream>>>(attn_W, align_w, u_v);

  // 3) encoder input preacts: Xe[s*16+b, :] = emb_enc[source] @ Wih.T + enc_b  (bf16)
  k_gemm<true,  true,  true,  false><<<dim3(G4/128, (Bsz*Ssz)/128), 256, 0, stream>>>(
      emb_enc, source, Ssz, nullptr, wE_ih, enc_b, nullptr, Xe, Bsz*Ssz, G4, Esz);

  // 4) decoder input preacts (embedding part): Xd[t*16+b, :] = emb_dec[tok] @ WihE.T (fp32)
  k_gemm<true,  false, false, false><<<dim3(G4/128, (TD*Bsz + 127)/128), 256, 0, stream>>>(
      emb_dec, target, Tsz, nullptr, wD_ihE, nullptr, Xdv, nullptr, TD*Bsz, G4, Esz);

  // 5) persistent recurrence: encoder 512 steps + attention + decoder 63 steps
  k_rec<<<dim3(GREC), 256, 0, stream>>>(wE_hh, wD_hh, Xe, Xdv, u_v, dec_Wih, dec_b,
                                        hbuf, enc_outs, scores, ctx, addc, Hd, flags);

  // 6) logits: out[b, t+1, :] = Hd[t*16+b, :] @ out_W.T + out_b
  k_gemm<false, false, true,  true ><<<dim3(Vsz/128, (TD*Bsz + 127)/128), 256, 0, stream>>>(
      nullptr, nullptr, 0, Hd, wOut, out_b, out, nullptr, TD*Bsz, Vsz, Hsz);

  (void)in_sizes; (void)n_in; (void)out_size; (void)ws_size;
}